// Round 2
// baseline (547.186 us; speedup 1.0000x reference)
//
#include <hip/hip_runtime.h>
#include <stdint.h>

#define C_CLASSES 1024
#define D_DIM     512
#define N_SUP     65536
#define N_QRY     65536
#define SLOTS     144   // per-class row-list capacity (mean 64, sd ~8 -> 10 sd margin)

typedef float f32x4 __attribute__((ext_vector_type(4)));
typedef float f32x16v __attribute__((ext_vector_type(16)));
typedef short bf16x8 __attribute__((ext_vector_type(8)));
typedef unsigned short u16x4 __attribute__((ext_vector_type(4)));
typedef unsigned short u16x8 __attribute__((ext_vector_type(8)));

#define GLOBAL_AS __attribute__((address_space(1)))
#define LDS_AS    __attribute__((address_space(3)))

__device__ inline void async_copy16(const void* g, void* l) {
    __builtin_amdgcn_global_load_lds((const GLOBAL_AS void*)g, (LDS_AS void*)l, 16, 0, 0);
}

// f32 -> bf16 round-to-nearest-even
__device__ inline unsigned short f2bf(float f) {
    union { float f; unsigned int u; } x; x.f = f;
    unsigned int u = x.u;
    return (unsigned short)((u + 0x7fffu + ((u >> 16) & 1u)) >> 16);
}

// ---------------------------------------------------------------------------
// Phase 1: q_sq per query row + f32->bf16 conversion of z_query into ws,
// with the counting-sort scatter fused into blocks 0..255.
// (cursors are zeroed by hipMemsetAsync in kernel_launch.)
// ---------------------------------------------------------------------------
template<bool CONV>
__global__ __launch_bounds__(256) void qsq_conv_kernel(
    const float* __restrict__ zq, float* __restrict__ qsq,
    unsigned short* __restrict__ Abf,
    const int* __restrict__ ys, int* __restrict__ cursors,
    int* __restrict__ rowlist)
{
    // fused scatter: 256 blocks x 256 threads cover all support rows
    if (blockIdx.x < N_SUP / 256) {
        int i = blockIdx.x * 256 + threadIdx.x;
        int c = ys[i];
        int slot = atomicAdd(&cursors[c], 1);
        if (slot < SLOTS) rowlist[c * SLOTS + slot] = i;
    }

    const int w    = threadIdx.x >> 6;
    const int lane = threadIdx.x & 63;
    const int row  = blockIdx.x * 4 + w;
    const f32x4* zp = (const f32x4*)(zq + (size_t)row * D_DIM);
    f32x4 a = zp[2 * lane];
    f32x4 b = zp[2 * lane + 1];
    if (CONV) {
        u16x8 p;
        p.s0 = f2bf(a.x); p.s1 = f2bf(a.y); p.s2 = f2bf(a.z); p.s3 = f2bf(a.w);
        p.s4 = f2bf(b.x); p.s5 = f2bf(b.y); p.s6 = f2bf(b.z); p.s7 = f2bf(b.w);
        *(u16x8*)(Abf + (size_t)row * D_DIM + lane * 8) = p;
    }
    float s = a.x*a.x + a.y*a.y + a.z*a.z + a.w*a.w
            + b.x*b.x + b.y*b.y + b.z*b.z + b.w*b.w;
    #pragma unroll
    for (int off = 32; off > 0; off >>= 1) s += __shfl_down(s, off, 64);
    if (lane == 0) qsq[row] = s;
}

// ---------------------------------------------------------------------------
// Phase 2: gather + mean. One block per class, 4 waves split the list.
// rowlist staged to LDS first; gather loop pipelined 2 rows deep so two
// HBM row-loads are in flight per wave.
// Emits protos bf16 [C][D] (B^T layout) and p_sq f32 [C].
// ---------------------------------------------------------------------------
__global__ __launch_bounds__(256) void proto_gather(
    const float* __restrict__ zs, const int* __restrict__ rowlist,
    const int* __restrict__ cursors, unsigned short* __restrict__ protos,
    float* __restrict__ psq)
{
    const int c    = blockIdx.x;
    const int tid  = threadIdx.x;
    const int w    = tid >> 6;
    const int lane = tid & 63;

    const int cnt = cursors[c];
    const int m   = cnt < SLOTS ? cnt : SLOTS;

    __shared__ int sRows[SLOTS];
    if (tid < m) sRows[tid] = rowlist[c * SLOTS + tid];
    __syncthreads();

    f32x4 s0 = {0.f, 0.f, 0.f, 0.f};
    f32x4 s1 = {0.f, 0.f, 0.f, 0.f};
    int j = w;
    for (; j + 4 < m; j += 8) {
        int r0 = sRows[j];
        int r1 = sRows[j + 4];
        const f32x4* z0 = (const f32x4*)(zs + (size_t)r0 * D_DIM);
        const f32x4* z1 = (const f32x4*)(zs + (size_t)r1 * D_DIM);
        f32x4 a0 = z0[lane], a1 = z0[64 + lane];
        f32x4 b0 = z1[lane], b1 = z1[64 + lane];
        s0 += a0; s1 += a1;
        s0 += b0; s1 += b1;
    }
    for (; j < m; j += 4) {
        int r = sRows[j];
        const f32x4* zp = (const f32x4*)(zs + (size_t)r * D_DIM);
        s0 += zp[lane];
        s1 += zp[64 + lane];
    }

    __shared__ float sAcc[4][D_DIM];
    ((f32x4*)&sAcc[w][0])[lane]      = s0;
    ((f32x4*)&sAcc[w][0])[64 + lane] = s1;
    __syncthreads();

    float inv = 1.0f / fmaxf((float)cnt, 1.0f);
    int t2 = tid + 256;
    float p0 = (sAcc[0][tid] + sAcc[1][tid] + sAcc[2][tid] + sAcc[3][tid]) * inv;
    float p1 = (sAcc[0][t2]  + sAcc[1][t2]  + sAcc[2][t2]  + sAcc[3][t2])  * inv;
    protos[(size_t)c * D_DIM + tid] = f2bf(p0);
    protos[(size_t)c * D_DIM + t2]  = f2bf(p1);

    float ps = p0 * p0 + p1 * p1;
    #pragma unroll
    for (int off = 32; off > 0; off >>= 1) ps += __shfl_down(ps, off, 64);
    __shared__ float sPs[4];
    if (lane == 0) sPs[w] = ps;
    __syncthreads();
    if (tid == 0) psq[c] = sPs[0] + sPs[1] + sPs[2] + sPs[3];
}

// ---------------------------------------------------------------------------
// Phase 3: GEMM  out[m][n] = 2*(q_m . p_n) - qsq[m] - psq[n]
// 128x128 block, BK=64, 4 waves 2x2 (wave = 64x64), 2x2 subtiles of
// mfma_f32_32x32x16_bf16, 16 MFMA per wave per K-iter.
// XCD-chunked blockIdx swizzle (T1): hw dispatch order round-robins XCDs,
// so remap hw id -> logical tile so each XCD gets a CONTIGUOUS chunk of
// 512 logical tiles. The 8 tiles sharing one 128-row A panel are then
// temporally adjacent on the SAME XCD -> panel hits that XCD's L2 instead
// of being re-fetched by 8 different L2s (4096 % 8 == 0 -> bijective).
// LDS 16B-chunks XOR-swizzled with the 8-slot involution slot = c ^ (r&7).
// async global_load_lds staging: LDS dest linear, global source pre-swizzled.
// ---------------------------------------------------------------------------
template<bool FAST>
__global__ __launch_bounds__(256) void gemm_kernel(
    const float* __restrict__ A32, const unsigned short* __restrict__ Abf,
    const unsigned short* __restrict__ Bp,
    const float* __restrict__ qsq, const float* __restrict__ psq,
    float* __restrict__ out)
{
    constexpr int BM = 128, BN = 128, BK = 64, K = D_DIM, NN = C_CLASSES;
    __shared__ __align__(16) unsigned short shA[BM * BK];
    __shared__ __align__(16) unsigned short shB[BN * BK];

    const int tid  = threadIdx.x;
    const int lane = tid & 63;
    const int w    = tid >> 6;
    const int wm   = w >> 1, wn = w & 1;
    const int l31  = lane & 31, half = lane >> 5;

    // T1 XCD-chunked swizzle: grid = (8, 512) -> 4096 tiles, 512 per XCD.
    const int bid  = blockIdx.y * gridDim.x + blockIdx.x;  // hw dispatch order
    const int swz  = (bid & 7) * ((C_CLASSES / BN) * (N_QRY / BM) / 8) + (bid >> 3);
    const int mBase = (swz >> 3) * BM;   // gridDim.x == 8 tiles in N
    const int nBase = (swz & 7) * BN;

    // async staging map: one copy fills 1 KiB = 8 rows x 128B.
    // lane -> row lane>>3 within the 8-row group, slot lane&7.
    const int srow = lane >> 3;                  // 0..7
    const int scg  = ((lane & 7) ^ srow) * 8;    // swizzled global chunk (elems)

    f32x16v acc[2][2];
    #pragma unroll
    for (int i = 0; i < 2; i++)
        #pragma unroll
        for (int j = 0; j < 2; j++)
            acc[i][j] = (f32x16v)(0.0f);

    for (int k0 = 0; k0 < K; k0 += BK) {
        __syncthreads();
        if (FAST) {
            #pragma unroll
            for (int t = 0; t < 4; t++) {
                int g = w * 4 + t;               // 16 groups of 8 rows
                async_copy16(Abf + (size_t)(mBase + g * 8 + srow) * K + k0 + scg,
                             &shA[g * 8 * BK]);
                async_copy16(Bp  + (size_t)(nBase + g * 8 + srow) * K + k0 + scg,
                             &shB[g * 8 * BK]);
            }
        } else {
            // stage A from f32 with conversion, honoring the swizzle
            #pragma unroll
            for (int t = 0; t < 4; t++) {
                int q = tid * 4 + t;             // chunk id 0..1023
                int r = q >> 3;                  // row 0..127
                int x = q & 7;                   // LDS slot
                int cg = x ^ (r & 7);
                const float* src = A32 + (size_t)(mBase + r) * K + k0 + cg * 8;
                f32x4 v0 = *(const f32x4*)src;
                f32x4 v1 = *(const f32x4*)(src + 4);
                u16x8 p;
                p.s0 = f2bf(v0.x); p.s1 = f2bf(v0.y); p.s2 = f2bf(v0.z); p.s3 = f2bf(v0.w);
                p.s4 = f2bf(v1.x); p.s5 = f2bf(v1.y); p.s6 = f2bf(v1.z); p.s7 = f2bf(v1.w);
                *(u16x8*)&shA[r * BK + x * 8] = p;
            }
            #pragma unroll
            for (int t = 0; t < 4; t++) {
                int g = w * 4 + t;
                async_copy16(Bp + (size_t)(nBase + g * 8 + srow) * K + k0 + scg,
                             &shB[g * 8 * BK]);
            }
        }
        __syncthreads();

        // fragments: A row = m (l31), k = ks*16 + half*8 + j
        bf16x8 af[2][4], bfv[2][4];
        #pragma unroll
        for (int i = 0; i < 2; i++) {
            int ra = wm * 64 + i * 32 + l31;
            int ga = ra & 7;
            int rb = wn * 64 + i * 32 + l31;
            int gb = rb & 7;
            #pragma unroll
            for (int ks = 0; ks < 4; ks++) {
                int c = ks * 2 + half;
                af[i][ks]  = *(const bf16x8*)&shA[ra * BK + ((c ^ ga) * 8)];
                bfv[i][ks] = *(const bf16x8*)&shB[rb * BK + ((c ^ gb) * 8)];
            }
        }
        #pragma unroll
        for (int ks = 0; ks < 4; ks++)
            #pragma unroll
            for (int i = 0; i < 2; i++)
                #pragma unroll
                for (int j = 0; j < 2; j++)
                    acc[i][j] = __builtin_amdgcn_mfma_f32_32x32x16_bf16(
                        af[i][ks], bfv[j][ks], acc[i][j], 0, 0, 0);
    }

    // epilogue: out = 2*acc - qsq[row] - psq[col]
    // C/D layout (verified m74/m101): col = lane&31, row = (reg&3)+8*(reg>>2)+4*half
    const int rowb = mBase + wm * 64;
    const int colb = nBase + wn * 64;
    float pv[2];
    #pragma unroll
    for (int j = 0; j < 2; j++) pv[j] = psq[colb + j * 32 + l31];
    #pragma unroll
    for (int i = 0; i < 2; i++) {
        #pragma unroll
        for (int rg = 0; rg < 4; rg++) {
            int rbase = rowb + i * 32 + rg * 8 + half * 4;
            f32x4 qv = *(const f32x4*)&qsq[rbase];
            #pragma unroll
            for (int rr = 0; rr < 4; rr++) {
                int reg = rg * 4 + rr;
                size_t rowoff = (size_t)(rbase + rr) * NN;
                #pragma unroll
                for (int j = 0; j < 2; j++) {
                    out[rowoff + colb + j * 32 + l31] =
                        2.0f * acc[i][j][reg] - qv[rr] - pv[j];
                }
            }
        }
    }
}

extern "C" void kernel_launch(void* const* d_in, const int* in_sizes, int n_in,
                              void* d_out, int out_size, void* d_ws, size_t ws_size,
                              hipStream_t stream) {
    const float* zs = (const float*)d_in[0];
    const int*   ys = (const int*)d_in[1];
    const float* zq = (const float*)d_in[2];
    float* out = (float*)d_out;

    const size_t szAbf     = (size_t)N_QRY * D_DIM * 2;       // 64 MiB
    const size_t szProtos  = (size_t)C_CLASSES * D_DIM * 2;   // 1 MiB
    const size_t szQsq     = (size_t)N_QRY * 4;               // 256 KiB
    const size_t szRowlist = (size_t)C_CLASSES * SLOTS * 4;   // 576 KiB
    const size_t szPsq     = 4096;
    const size_t szCur     = 4096;

    const size_t needFast = szAbf + szProtos + szQsq + szRowlist + szPsq + szCur;
    const bool fast = ws_size >= needFast;

    char* ws = (char*)d_ws;
    unsigned short* Abf = (unsigned short*)ws;                 // fast path only
    char* base = fast ? ws + szAbf : ws;
    unsigned short* protos = (unsigned short*)base;
    float* qsq  = (float*)(base + szProtos);
    int*   rowlist = (int*)(base + szProtos + szQsq);
    float* psq  = (float*)(base + szProtos + szQsq + szRowlist);
    int*   cursors = (int*)(base + szProtos + szQsq + szRowlist + szPsq);

    // zero class cursors (capture-safe async memset replaces init kernel)
    hipMemsetAsync(cursors, 0, C_CLASSES * sizeof(int), stream);

    if (fast)
        qsq_conv_kernel<true><<<N_QRY / 4, 256, 0, stream>>>(
            zq, qsq, Abf, ys, cursors, rowlist);
    else
        qsq_conv_kernel<false><<<N_QRY / 4, 256, 0, stream>>>(
            zq, qsq, nullptr, ys, cursors, rowlist);
    proto_gather<<<C_CLASSES, 256, 0, stream>>>(zs, rowlist, cursors, protos, psq);
    if (fast)
        gemm_kernel<true><<<dim3(C_CLASSES / 128, N_QRY / 128), 256, 0, stream>>>(
            nullptr, Abf, protos, qsq, psq, out);
    else
        gemm_kernel<false><<<dim3(C_CLASSES / 128, N_QRY / 128), 256, 0, stream>>>(
            zq, nullptr, protos, qsq, psq, out);
}

// Round 3
// 541.101 us; speedup vs baseline: 1.0112x; 1.0112x over previous
//
#include <hip/hip_runtime.h>
#include <stdint.h>

#define C_CLASSES 1024
#define D_DIM     512
#define N_SUP     65536
#define N_QRY     65536
#define SLOTS     144   // per-class row-list capacity (mean 64, sd ~8 -> 10 sd margin)

typedef float f32x4 __attribute__((ext_vector_type(4)));
typedef float f32x16v __attribute__((ext_vector_type(16)));
typedef short bf16x8 __attribute__((ext_vector_type(8)));
typedef unsigned short u16x4 __attribute__((ext_vector_type(4)));
typedef unsigned short u16x8 __attribute__((ext_vector_type(8)));

#define GLOBAL_AS __attribute__((address_space(1)))
#define LDS_AS    __attribute__((address_space(3)))

__device__ inline void async_copy16(const void* g, void* l) {
    __builtin_amdgcn_global_load_lds((const GLOBAL_AS void*)g, (LDS_AS void*)l, 16, 0, 0);
}

// f32 -> bf16 round-to-nearest-even
__device__ inline unsigned short f2bf(float f) {
    union { float f; unsigned int u; } x; x.f = f;
    unsigned int u = x.u;
    return (unsigned short)((u + 0x7fffu + ((u >> 16) & 1u)) >> 16);
}

// ---------------------------------------------------------------------------
// Phase 1: q_sq per query row + f32->bf16 conversion of z_query into ws,
// with the counting-sort scatter fused into blocks 0..255.
// (cursors are zeroed by hipMemsetAsync in kernel_launch.)
// ---------------------------------------------------------------------------
template<bool CONV>
__global__ __launch_bounds__(256) void qsq_conv_kernel(
    const float* __restrict__ zq, float* __restrict__ qsq,
    unsigned short* __restrict__ Abf,
    const int* __restrict__ ys, int* __restrict__ cursors,
    int* __restrict__ rowlist)
{
    // fused scatter: 256 blocks x 256 threads cover all support rows
    if (blockIdx.x < N_SUP / 256) {
        int i = blockIdx.x * 256 + threadIdx.x;
        int c = ys[i];
        int slot = atomicAdd(&cursors[c], 1);
        if (slot < SLOTS) rowlist[c * SLOTS + slot] = i;
    }

    const int w    = threadIdx.x >> 6;
    const int lane = threadIdx.x & 63;
    const int row  = blockIdx.x * 4 + w;
    const f32x4* zp = (const f32x4*)(zq + (size_t)row * D_DIM);
    f32x4 a = zp[2 * lane];
    f32x4 b = zp[2 * lane + 1];
    if (CONV) {
        u16x8 p;
        p.s0 = f2bf(a.x); p.s1 = f2bf(a.y); p.s2 = f2bf(a.z); p.s3 = f2bf(a.w);
        p.s4 = f2bf(b.x); p.s5 = f2bf(b.y); p.s6 = f2bf(b.z); p.s7 = f2bf(b.w);
        *(u16x8*)(Abf + (size_t)row * D_DIM + lane * 8) = p;
    }
    float s = a.x*a.x + a.y*a.y + a.z*a.z + a.w*a.w
            + b.x*b.x + b.y*b.y + b.z*b.z + b.w*b.w;
    #pragma unroll
    for (int off = 32; off > 0; off >>= 1) s += __shfl_down(s, off, 64);
    if (lane == 0) qsq[row] = s;
}

// ---------------------------------------------------------------------------
// Phase 2: gather + mean. One block per class, 4 waves split the list.
// ---------------------------------------------------------------------------
__global__ __launch_bounds__(256) void proto_gather(
    const float* __restrict__ zs, const int* __restrict__ rowlist,
    const int* __restrict__ cursors, unsigned short* __restrict__ protos,
    float* __restrict__ psq)
{
    const int c    = blockIdx.x;
    const int tid  = threadIdx.x;
    const int w    = tid >> 6;
    const int lane = tid & 63;

    const int cnt = cursors[c];
    const int m   = cnt < SLOTS ? cnt : SLOTS;

    __shared__ int sRows[SLOTS];
    if (tid < m) sRows[tid] = rowlist[c * SLOTS + tid];
    __syncthreads();

    f32x4 s0 = {0.f, 0.f, 0.f, 0.f};
    f32x4 s1 = {0.f, 0.f, 0.f, 0.f};
    int j = w;
    for (; j + 4 < m; j += 8) {
        int r0 = sRows[j];
        int r1 = sRows[j + 4];
        const f32x4* z0 = (const f32x4*)(zs + (size_t)r0 * D_DIM);
        const f32x4* z1 = (const f32x4*)(zs + (size_t)r1 * D_DIM);
        f32x4 a0 = z0[lane], a1 = z0[64 + lane];
        f32x4 b0 = z1[lane], b1 = z1[64 + lane];
        s0 += a0; s1 += a1;
        s0 += b0; s1 += b1;
    }
    for (; j < m; j += 4) {
        int r = sRows[j];
        const f32x4* zp = (const f32x4*)(zs + (size_t)r * D_DIM);
        s0 += zp[lane];
        s1 += zp[64 + lane];
    }

    __shared__ float sAcc[4][D_DIM];
    ((f32x4*)&sAcc[w][0])[lane]      = s0;
    ((f32x4*)&sAcc[w][0])[64 + lane] = s1;
    __syncthreads();

    float inv = 1.0f / fmaxf((float)cnt, 1.0f);
    int t2 = tid + 256;
    float p0 = (sAcc[0][tid] + sAcc[1][tid] + sAcc[2][tid] + sAcc[3][tid]) * inv;
    float p1 = (sAcc[0][t2]  + sAcc[1][t2]  + sAcc[2][t2]  + sAcc[3][t2])  * inv;
    protos[(size_t)c * D_DIM + tid] = f2bf(p0);
    protos[(size_t)c * D_DIM + t2]  = f2bf(p1);

    float ps = p0 * p0 + p1 * p1;
    #pragma unroll
    for (int off = 32; off > 0; off >>= 1) ps += __shfl_down(ps, off, 64);
    __shared__ float sPs[4];
    if (lane == 0) sPs[w] = ps;
    __syncthreads();
    if (tid == 0) psq[c] = sPs[0] + sPs[1] + sPs[2] + sPs[3];
}

// ---------------------------------------------------------------------------
// Phase 3 (FAST): 256x256 deep-pipelined GEMM, plain-HIP port of the
// 8-phase schedule (T3+T4+T5).  out[m][n] = 2*(q_m . p_n) - qsq[m] - psq[n]
//
// BM=BN=256, BK=64, 8 waves (2M x 4N), per-wave output 128x64 via 4x2
// frags of mfma_f32_32x32x16_bf16.  LDS = 2 x (A 32K + B 32K) = 128 KiB
// double-buffered over K-tiles.  Per K-tile kt: 4 phases, phase p:
//   { ds_read A-frags m=p (+ all B-frags at p0)  |  stage 1 half-tile of
//     kt+1 }  -> s_barrier -> setprio(1) 8 MFMA setprio(0)
//   -> lgkmcnt(0) [+ vmcnt(0) at p3, hidden under this phase's MFMA]
//   -> s_barrier
// Raw barriers + explicit asm waits (NOT __syncthreads) so the global
// load queue is never drained mid-tile except once per K-tile at p3.
// LDS chunk swizzle slot = cc ^ (r&7): the 32-lane b128 frag read spreads
// 4 lanes per 4-bank group = conflict-free at b128 throughput.
// global_load_lds dest is linear; global source is pre-swizzled (rule 21).
// ---------------------------------------------------------------------------
__device__ __forceinline__ void stage_half(
    const unsigned short* __restrict__ src,   // Abf or Bp (global)
    unsigned short* dstTile,                  // &shX[buf][0]
    int rowBase,                              // h*128 + (w*2+t)*8 (mult of 8)
    size_t gBase,                             // mBase or nBase
    int k0, int srow, int scg)
{
    async_copy16(src + (gBase + (size_t)(rowBase + srow)) * D_DIM + k0 + scg,
                 dstTile + (size_t)rowBase * 64);
}

__global__ __launch_bounds__(512, 2) void gemm256_kernel(
    const unsigned short* __restrict__ Abf,
    const unsigned short* __restrict__ Bp,
    const float* __restrict__ qsq, const float* __restrict__ psq,
    float* __restrict__ out)
{
    constexpr int BM = 256, BN = 256, BK = 64, K = D_DIM, NN = C_CLASSES;
    constexpr int NKT = K / BK;                 // 8 K-tiles
    __shared__ __align__(16) unsigned short shA[2][BM * BK];   // 2 x 32 KiB
    __shared__ __align__(16) unsigned short shB[2][BN * BK];   // 2 x 32 KiB

    const int tid  = threadIdx.x;
    const int lane = tid & 63;
    const int w    = tid >> 6;              // 0..7
    const int wm   = w >> 2, wn = w & 3;    // 2M x 4N wave grid
    const int l31  = lane & 31, half = lane >> 5;
    const int mBase = blockIdx.y * BM;
    const int nBase = blockIdx.x * BN;

    // staging lane map: copy = 1 KiB = 8 rows x 128B; lane -> row l>>3,
    // slot l&7; global chunk pre-swizzled so LDS slot s holds chunk s^(r&7).
    const int srow = lane >> 3;
    const int scg  = ((lane & 7) ^ srow) * 8;

    f32x16v acc[4][2];
    #pragma unroll
    for (int i = 0; i < 4; i++)
        #pragma unroll
        for (int j = 0; j < 2; j++)
            acc[i][j] = (f32x16v)(0.0f);

    // ---- prologue: stage K-tile 0 into buffer 0, full drain ----
    #pragma unroll
    for (int t = 0; t < 2; t++) {
        int rb = (w * 2 + t) * 8;
        stage_half(Abf, &shA[0][0], rb,       mBase, 0, srow, scg);
        stage_half(Abf, &shA[0][0], 128 + rb, mBase, 0, srow, scg);
        stage_half(Bp,  &shB[0][0], rb,       nBase, 0, srow, scg);
        stage_half(Bp,  &shB[0][0], 128 + rb, nBase, 0, srow, scg);
    }
    asm volatile("s_waitcnt vmcnt(0)" ::: "memory");
    __builtin_amdgcn_s_barrier();

    // ---- main loop over K-tiles ----
    for (int kt = 0; kt < NKT; ++kt) {
        const int kn = kt + 1;
        unsigned short* curA = &shA[kt & 1][0];
        unsigned short* curB = &shB[kt & 1][0];
        unsigned short* nxtA = &shA[kn & 1][0];
        unsigned short* nxtB = &shB[kn & 1][0];

        bf16x8 bfv[2][4];

        #pragma unroll
        for (int p = 0; p < 4; ++p) {
            // --- ds_read this phase's fragments (from current buffer) ---
            bf16x8 af[4];
            const int ra = wm * 128 + p * 32 + l31;
            const int ga = ra & 7;
            #pragma unroll
            for (int ks = 0; ks < 4; ks++)
                af[ks] = *(const bf16x8*)&curA[ra * BK + (((ks * 2 + half) ^ ga) * 8)];
            if (p == 0) {
                #pragma unroll
                for (int n = 0; n < 2; n++) {
                    const int rb = wn * 64 + n * 32 + l31;
                    const int gb = rb & 7;
                    #pragma unroll
                    for (int ks = 0; ks < 4; ks++)
                        bfv[n][ks] = *(const bf16x8*)&curB[rb * BK + (((ks * 2 + half) ^ gb) * 8)];
                }
            }

            // --- stage one half-tile of K-tile kt+1 (p0:A0 p1:A1 p2:B0 p3:B1) ---
            if (kn < NKT) {
                const unsigned short* srcT = (p < 2) ? Abf : Bp;
                unsigned short* dstT = (p < 2) ? nxtA : nxtB;
                const size_t gb = (p < 2) ? (size_t)mBase : (size_t)nBase;
                const int h = (p & 1) * 128;
                #pragma unroll
                for (int t = 0; t < 2; t++)
                    stage_half(srcT, dstT, h + (w * 2 + t) * 8, gb, kn * BK, srow, scg);
            }

            asm volatile("" ::: "memory");
            __builtin_amdgcn_s_barrier();

            // --- MFMA cluster (compiler inserts lgkmcnt before uses) ---
            __builtin_amdgcn_s_setprio(1);
            #pragma unroll
            for (int ks = 0; ks < 4; ks++)
                #pragma unroll
                for (int n = 0; n < 2; n++)
                    acc[p][n] = __builtin_amdgcn_mfma_f32_32x32x16_bf16(
                        af[ks], bfv[n][ks], acc[p][n], 0, 0, 0);
            __builtin_amdgcn_s_setprio(0);

            // ensure own LDS reads done before others may overwrite;
            // at p3 also require all of kt+1's copies landed (drain hidden
            // under this phase's MFMA).
            if (p == 3)
                asm volatile("s_waitcnt vmcnt(0) lgkmcnt(0)" ::: "memory");
            else
                asm volatile("s_waitcnt lgkmcnt(0)" ::: "memory");
            __builtin_amdgcn_s_barrier();
        }
    }

    // epilogue: out = 2*acc - qsq[row] - psq[col]
    // C/D layout (verified m74/m101): col = lane&31, row = (reg&3)+8*(reg>>2)+4*half
    const int rowb = mBase + wm * 128;
    const int colb = nBase + wn * 64;
    float pv[2];
    #pragma unroll
    for (int n = 0; n < 2; n++) pv[n] = psq[colb + n * 32 + l31];
    #pragma unroll
    for (int m = 0; m < 4; m++) {
        #pragma unroll
        for (int rg = 0; rg < 4; rg++) {
            int rbase = rowb + m * 32 + rg * 8 + half * 4;
            f32x4 qv = *(const f32x4*)&qsq[rbase];
            #pragma unroll
            for (int rr = 0; rr < 4; rr++) {
                int reg = rg * 4 + rr;
                size_t rowoff = (size_t)(rbase + rr) * NN;
                #pragma unroll
                for (int n = 0; n < 2; n++) {
                    out[rowoff + colb + n * 32 + l31] =
                        2.0f * acc[m][n][reg] - qv[rr] - pv[n];
                }
            }
        }
    }
}

// ---------------------------------------------------------------------------
// Phase 3 (fallback, ws too small): previous 128x128 kernel reading zq f32.
// ---------------------------------------------------------------------------
__global__ __launch_bounds__(256) void gemm_kernel_slow(
    const float* __restrict__ A32,
    const unsigned short* __restrict__ Bp,
    const float* __restrict__ qsq, const float* __restrict__ psq,
    float* __restrict__ out)
{
    constexpr int BM = 128, BN = 128, BK = 64, K = D_DIM, NN = C_CLASSES;
    __shared__ __align__(16) unsigned short shA[BM * BK];
    __shared__ __align__(16) unsigned short shB[BN * BK];

    const int tid  = threadIdx.x;
    const int lane = tid & 63;
    const int w    = tid >> 6;
    const int wm   = w >> 1, wn = w & 1;
    const int l31  = lane & 31, half = lane >> 5;
    const int mBase = blockIdx.y * BM;
    const int nBase = blockIdx.x * BN;

    const int srow = lane >> 3;
    const int scg  = ((lane & 7) ^ srow) * 8;

    f32x16v acc[2][2];
    #pragma unroll
    for (int i = 0; i < 2; i++)
        #pragma unroll
        for (int j = 0; j < 2; j++)
            acc[i][j] = (f32x16v)(0.0f);

    for (int k0 = 0; k0 < K; k0 += BK) {
        __syncthreads();
        #pragma unroll
        for (int t = 0; t < 4; t++) {
            int q = tid * 4 + t;
            int r = q >> 3;
            int x = q & 7;
            int cg = x ^ (r & 7);
            const float* src = A32 + (size_t)(mBase + r) * K + k0 + cg * 8;
            f32x4 v0 = *(const f32x4*)src;
            f32x4 v1 = *(const f32x4*)(src + 4);
            u16x8 p;
            p.s0 = f2bf(v0.x); p.s1 = f2bf(v0.y); p.s2 = f2bf(v0.z); p.s3 = f2bf(v0.w);
            p.s4 = f2bf(v1.x); p.s5 = f2bf(v1.y); p.s6 = f2bf(v1.z); p.s7 = f2bf(v1.w);
            *(u16x8*)&shA[r * BK + x * 8] = p;
        }
        #pragma unroll
        for (int t = 0; t < 4; t++) {
            int g = w * 4 + t;
            async_copy16(Bp + (size_t)(nBase + g * 8 + srow) * K + k0 + scg,
                         &shB[g * 8 * BK]);
        }
        __syncthreads();

        bf16x8 af[2][4], bfv[2][4];
        #pragma unroll
        for (int i = 0; i < 2; i++) {
            int ra = wm * 64 + i * 32 + l31;
            int ga = ra & 7;
            int rb = wn * 64 + i * 32 + l31;
            int gb = rb & 7;
            #pragma unroll
            for (int ks = 0; ks < 4; ks++) {
                int c = ks * 2 + half;
                af[i][ks]  = *(const bf16x8*)&shA[ra * BK + ((c ^ ga) * 8)];
                bfv[i][ks] = *(const bf16x8*)&shB[rb * BK + ((c ^ gb) * 8)];
            }
        }
        #pragma unroll
        for (int ks = 0; ks < 4; ks++)
            #pragma unroll
            for (int i = 0; i < 2; i++)
                #pragma unroll
                for (int j = 0; j < 2; j++)
                    acc[i][j] = __builtin_amdgcn_mfma_f32_32x32x16_bf16(
                        af[i][ks], bfv[j][ks], acc[i][j], 0, 0, 0);
    }

    const int rowb = mBase + wm * 64;
    const int colb = nBase + wn * 64;
    float pv[2];
    #pragma unroll
    for (int j = 0; j < 2; j++) pv[j] = psq[colb + j * 32 + l31];
    #pragma unroll
    for (int i = 0; i < 2; i++) {
        #pragma unroll
        for (int rg = 0; rg < 4; rg++) {
            int rbase = rowb + i * 32 + rg * 8 + half * 4;
            f32x4 qv = *(const f32x4*)&qsq[rbase];
            #pragma unroll
            for (int rr = 0; rr < 4; rr++) {
                int reg = rg * 4 + rr;
                size_t rowoff = (size_t)(rbase + rr) * NN;
                #pragma unroll
                for (int j = 0; j < 2; j++) {
                    out[rowoff + colb + j * 32 + l31] =
                        2.0f * acc[i][j][reg] - qv[rr] - pv[j];
                }
            }
        }
    }
}

extern "C" void kernel_launch(void* const* d_in, const int* in_sizes, int n_in,
                              void* d_out, int out_size, void* d_ws, size_t ws_size,
                              hipStream_t stream) {
    const float* zs = (const float*)d_in[0];
    const int*   ys = (const int*)d_in[1];
    const float* zq = (const float*)d_in[2];
    float* out = (float*)d_out;

    const size_t szAbf     = (size_t)N_QRY * D_DIM * 2;       // 64 MiB
    const size_t szProtos  = (size_t)C_CLASSES * D_DIM * 2;   // 1 MiB
    const size_t szQsq     = (size_t)N_QRY * 4;               // 256 KiB
    const size_t szRowlist = (size_t)C_CLASSES * SLOTS * 4;   // 576 KiB
    const size_t szPsq     = 4096;
    const size_t szCur     = 4096;

    const size_t needFast = szAbf + szProtos + szQsq + szRowlist + szPsq + szCur;
    const bool fast = ws_size >= needFast;

    char* ws = (char*)d_ws;
    unsigned short* Abf = (unsigned short*)ws;                 // fast path only
    char* base = fast ? ws + szAbf : ws;
    unsigned short* protos = (unsigned short*)base;
    float* qsq  = (float*)(base + szProtos);
    int*   rowlist = (int*)(base + szProtos + szQsq);
    float* psq  = (float*)(base + szProtos + szQsq + szRowlist);
    int*   cursors = (int*)(base + szProtos + szQsq + szRowlist + szPsq);

    // zero class cursors (capture-safe async memset)
    hipMemsetAsync(cursors, 0, C_CLASSES * sizeof(int), stream);

    if (fast)
        qsq_conv_kernel<true><<<N_QRY / 4, 256, 0, stream>>>(
            zq, qsq, Abf, ys, cursors, rowlist);
    else
        qsq_conv_kernel<false><<<N_QRY / 4, 256, 0, stream>>>(
            zq, qsq, nullptr, ys, cursors, rowlist);
    proto_gather<<<C_CLASSES, 256, 0, stream>>>(zs, rowlist, cursors, protos, psq);
    if (fast)
        gemm256_kernel<<<dim3(C_CLASSES / 256, N_QRY / 256), 512, 0, stream>>>(
            Abf, protos, qsq, psq, out);
    else
        gemm_kernel_slow<<<dim3(C_CLASSES / 128, N_QRY / 128), 256, 0, stream>>>(
            zq, protos, qsq, psq, out);
}

// Round 4
// 535.651 us; speedup vs baseline: 1.0215x; 1.0102x over previous
//
#include <hip/hip_runtime.h>
#include <stdint.h>

#define C_CLASSES 1024
#define D_DIM     512
#define N_SUP     65536
#define N_QRY     65536
#define SLOTS     144   // per-class row-list capacity (mean 64, sd ~8 -> 10 sd margin)

typedef float f32x4 __attribute__((ext_vector_type(4)));
typedef float f32x16v __attribute__((ext_vector_type(16)));
typedef short bf16x8 __attribute__((ext_vector_type(8)));
typedef unsigned short u16x4 __attribute__((ext_vector_type(4)));
typedef unsigned short u16x8 __attribute__((ext_vector_type(8)));

#define GLOBAL_AS __attribute__((address_space(1)))
#define LDS_AS    __attribute__((address_space(3)))

__device__ inline void async_copy16(const void* g, void* l) {
    __builtin_amdgcn_global_load_lds((const GLOBAL_AS void*)g, (LDS_AS void*)l, 16, 0, 0);
}

// f32 -> bf16 round-to-nearest-even
__device__ inline unsigned short f2bf(float f) {
    union { float f; unsigned int u; } x; x.f = f;
    unsigned int u = x.u;
    return (unsigned short)((u + 0x7fffu + ((u >> 16) & 1u)) >> 16);
}

// ---------------------------------------------------------------------------
// Phase 0b: counting-sort scatter (tiny; unblocks the gather half of the
// fused kernel). cursors zeroed by hipMemsetAsync beforehand.
// ---------------------------------------------------------------------------
__global__ __launch_bounds__(256) void scatter_kernel(
    const int* __restrict__ ys, int* __restrict__ cursors,
    int* __restrict__ rowlist)
{
    int i = blockIdx.x * 256 + threadIdx.x;
    int c = ys[i];
    int slot = atomicAdd(&cursors[c], 1);
    if (slot < SLOTS) rowlist[c * SLOTS + slot] = i;
}

// ---------------------------------------------------------------------------
// Phase 1+2 fused: blocks 0..1023 run the per-class gather+mean (latency-
// bound random 2KiB reads of zs); blocks 1024.. run qsq + f32->bf16 conv
// (streaming reads of zq).  Gather blocks dispatch first, so their
// dependent-load latency hides under the qsq stream and the two phases
// share HBM bandwidth instead of each paying its own ramp.
// ---------------------------------------------------------------------------
template<bool CONV>
__global__ __launch_bounds__(256) void fused_qsq_gather(
    const float* __restrict__ zq, float* __restrict__ qsq,
    unsigned short* __restrict__ Abf,
    const float* __restrict__ zs, const int* __restrict__ rowlist,
    const int* __restrict__ cursors, unsigned short* __restrict__ protos,
    float* __restrict__ psq)
{
    const int tid  = threadIdx.x;
    const int w    = tid >> 6;
    const int lane = tid & 63;

    if (blockIdx.x < C_CLASSES) {
        // ---- gather + mean for class c ----
        const int c   = blockIdx.x;
        const int cnt = cursors[c];
        const int m   = cnt < SLOTS ? cnt : SLOTS;

        __shared__ int sRows[SLOTS];
        if (tid < m) sRows[tid] = rowlist[c * SLOTS + tid];
        __syncthreads();

        f32x4 s0 = {0.f, 0.f, 0.f, 0.f};
        f32x4 s1 = {0.f, 0.f, 0.f, 0.f};
        int j = w;
        for (; j + 4 < m; j += 8) {
            int r0 = sRows[j];
            int r1 = sRows[j + 4];
            const f32x4* z0 = (const f32x4*)(zs + (size_t)r0 * D_DIM);
            const f32x4* z1 = (const f32x4*)(zs + (size_t)r1 * D_DIM);
            f32x4 a0 = z0[lane], a1 = z0[64 + lane];
            f32x4 b0 = z1[lane], b1 = z1[64 + lane];
            s0 += a0; s1 += a1;
            s0 += b0; s1 += b1;
        }
        for (; j < m; j += 4) {
            int r = sRows[j];
            const f32x4* zp = (const f32x4*)(zs + (size_t)r * D_DIM);
            s0 += zp[lane];
            s1 += zp[64 + lane];
        }

        __shared__ float sAcc[4][D_DIM];
        ((f32x4*)&sAcc[w][0])[lane]      = s0;
        ((f32x4*)&sAcc[w][0])[64 + lane] = s1;
        __syncthreads();

        float inv = 1.0f / fmaxf((float)cnt, 1.0f);
        int t2 = tid + 256;
        float p0 = (sAcc[0][tid] + sAcc[1][tid] + sAcc[2][tid] + sAcc[3][tid]) * inv;
        float p1 = (sAcc[0][t2]  + sAcc[1][t2]  + sAcc[2][t2]  + sAcc[3][t2])  * inv;
        protos[(size_t)c * D_DIM + tid] = f2bf(p0);
        protos[(size_t)c * D_DIM + t2]  = f2bf(p1);

        float ps = p0 * p0 + p1 * p1;
        #pragma unroll
        for (int off = 32; off > 0; off >>= 1) ps += __shfl_down(ps, off, 64);
        __shared__ float sPs[4];
        if (lane == 0) sPs[w] = ps;
        __syncthreads();
        if (tid == 0) psq[c] = sPs[0] + sPs[1] + sPs[2] + sPs[3];
        return;
    }

    // ---- q_sq + conversion, 4 query rows per block ----
    const int row = (blockIdx.x - C_CLASSES) * 4 + w;
    const f32x4* zp = (const f32x4*)(zq + (size_t)row * D_DIM);
    f32x4 a = zp[2 * lane];
    f32x4 b = zp[2 * lane + 1];
    if (CONV) {
        u16x8 p;
        p.s0 = f2bf(a.x); p.s1 = f2bf(a.y); p.s2 = f2bf(a.z); p.s3 = f2bf(a.w);
        p.s4 = f2bf(b.x); p.s5 = f2bf(b.y); p.s6 = f2bf(b.z); p.s7 = f2bf(b.w);
        *(u16x8*)(Abf + (size_t)row * D_DIM + lane * 8) = p;
    }
    float s = a.x*a.x + a.y*a.y + a.z*a.z + a.w*a.w
            + b.x*b.x + b.y*b.y + b.z*b.z + b.w*b.w;
    #pragma unroll
    for (int off = 32; off > 0; off >>= 1) s += __shfl_down(s, off, 64);
    if (lane == 0) qsq[row] = s;
}

// ---------------------------------------------------------------------------
// Phase 3 (FAST): 256x256 deep-pipelined GEMM (T3+T4+T5 schedule).
// out[m][n] = 2*(q_m . p_n) - qsq[m] - psq[n]
// BM=BN=256, BK=64, 8 waves (2M x 4N), per-wave 128x64 via 4x2 frags of
// mfma_f32_32x32x16_bf16.  LDS 128 KiB double-buffered.
// All 8 next-tile global_load_lds are issued at phases 0-1 (A at p0, B at
// p1) so the p3 vmcnt(0) drain finds them already landed (~3 phases of
// latency cover instead of 0 at 1-block/CU occupancy).
// LDS chunk swizzle slot = cc ^ (r&7); staging dest linear, global source
// pre-swizzled (rule 21).
// ---------------------------------------------------------------------------
__device__ __forceinline__ void stage_half(
    const unsigned short* __restrict__ src,   // Abf or Bp (global)
    unsigned short* dstTile,                  // &shX[buf][0]
    int rowBase,                              // h*128 + (w*2+t)*8 (mult of 8)
    size_t gBase,                             // mBase or nBase
    int k0, int srow, int scg)
{
    async_copy16(src + (gBase + (size_t)(rowBase + srow)) * D_DIM + k0 + scg,
                 dstTile + (size_t)rowBase * 64);
}

__global__ __launch_bounds__(512, 2) void gemm256_kernel(
    const unsigned short* __restrict__ Abf,
    const unsigned short* __restrict__ Bp,
    const float* __restrict__ qsq, const float* __restrict__ psq,
    float* __restrict__ out)
{
    constexpr int BM = 256, BN = 256, BK = 64, K = D_DIM, NN = C_CLASSES;
    constexpr int NKT = K / BK;                 // 8 K-tiles
    __shared__ __align__(16) unsigned short shA[2][BM * BK];   // 2 x 32 KiB
    __shared__ __align__(16) unsigned short shB[2][BN * BK];   // 2 x 32 KiB

    const int tid  = threadIdx.x;
    const int lane = tid & 63;
    const int w    = tid >> 6;              // 0..7
    const int wm   = w >> 2, wn = w & 3;    // 2M x 4N wave grid
    const int l31  = lane & 31, half = lane >> 5;
    const int mBase = blockIdx.y * BM;
    const int nBase = blockIdx.x * BN;

    // staging lane map: copy = 1 KiB = 8 rows x 128B; lane -> row l>>3,
    // slot l&7; global chunk pre-swizzled so LDS slot s holds chunk s^(r&7).
    const int srow = lane >> 3;
    const int scg  = ((lane & 7) ^ srow) * 8;

    f32x16v acc[4][2];
    #pragma unroll
    for (int i = 0; i < 4; i++)
        #pragma unroll
        for (int j = 0; j < 2; j++)
            acc[i][j] = (f32x16v)(0.0f);

    // ---- prologue: stage K-tile 0 into buffer 0, full drain ----
    #pragma unroll
    for (int t = 0; t < 2; t++) {
        int rb = (w * 2 + t) * 8;
        stage_half(Abf, &shA[0][0], rb,       mBase, 0, srow, scg);
        stage_half(Abf, &shA[0][0], 128 + rb, mBase, 0, srow, scg);
        stage_half(Bp,  &shB[0][0], rb,       nBase, 0, srow, scg);
        stage_half(Bp,  &shB[0][0], 128 + rb, nBase, 0, srow, scg);
    }
    asm volatile("s_waitcnt vmcnt(0)" ::: "memory");
    __builtin_amdgcn_s_barrier();

    // ---- main loop over K-tiles ----
    for (int kt = 0; kt < NKT; ++kt) {
        const int kn = kt + 1;
        unsigned short* curA = &shA[kt & 1][0];
        unsigned short* curB = &shB[kt & 1][0];
        unsigned short* nxtA = &shA[kn & 1][0];
        unsigned short* nxtB = &shB[kn & 1][0];

        bf16x8 bfv[2][4];

        #pragma unroll
        for (int p = 0; p < 4; ++p) {
            // --- ds_read this phase's fragments (from current buffer) ---
            bf16x8 af[4];
            const int ra = wm * 128 + p * 32 + l31;
            const int ga = ra & 7;
            #pragma unroll
            for (int ks = 0; ks < 4; ks++)
                af[ks] = *(const bf16x8*)&curA[ra * BK + (((ks * 2 + half) ^ ga) * 8)];
            if (p == 0) {
                #pragma unroll
                for (int n = 0; n < 2; n++) {
                    const int rb = wn * 64 + n * 32 + l31;
                    const int gb = rb & 7;
                    #pragma unroll
                    for (int ks = 0; ks < 4; ks++)
                        bfv[n][ks] = *(const bf16x8*)&curB[rb * BK + (((ks * 2 + half) ^ gb) * 8)];
                }
            }

            // --- stage K-tile kt+1: all A at p0, all B at p1 (early issue
            //     so the p3 drain has ~3 phases of latency cover) ---
            if (kn < NKT && p < 2) {
                const unsigned short* srcT = (p == 0) ? Abf : Bp;
                unsigned short* dstT = (p == 0) ? nxtA : nxtB;
                const size_t gb = (p == 0) ? (size_t)mBase : (size_t)nBase;
                #pragma unroll
                for (int t = 0; t < 2; t++) {
                    int rb = (w * 2 + t) * 8;
                    stage_half(srcT, dstT, rb,       gb, kn * BK, srow, scg);
                    stage_half(srcT, dstT, 128 + rb, gb, kn * BK, srow, scg);
                }
            }

            asm volatile("" ::: "memory");
            __builtin_amdgcn_s_barrier();

            // --- MFMA cluster ---
            __builtin_amdgcn_s_setprio(1);
            #pragma unroll
            for (int ks = 0; ks < 4; ks++)
                #pragma unroll
                for (int n = 0; n < 2; n++)
                    acc[p][n] = __builtin_amdgcn_mfma_f32_32x32x16_bf16(
                        af[ks], bfv[n][ks], acc[p][n], 0, 0, 0);
            __builtin_amdgcn_s_setprio(0);

            // own LDS reads done before others may overwrite; at p3 also
            // require all of kt+1's copies landed (issued >=2 phases ago).
            if (p == 3)
                asm volatile("s_waitcnt vmcnt(0) lgkmcnt(0)" ::: "memory");
            else
                asm volatile("s_waitcnt lgkmcnt(0)" ::: "memory");
            __builtin_amdgcn_s_barrier();
        }
    }

    // epilogue: out = 2*acc - qsq[row] - psq[col]
    // C/D layout (verified m74/m101): col = lane&31, row = (reg&3)+8*(reg>>2)+4*half
    const int rowb = mBase + wm * 128;
    const int colb = nBase + wn * 64;
    float pv[2];
    #pragma unroll
    for (int n = 0; n < 2; n++) pv[n] = psq[colb + n * 32 + l31];
    #pragma unroll
    for (int m = 0; m < 4; m++) {
        #pragma unroll
        for (int rg = 0; rg < 4; rg++) {
            int rbase = rowb + m * 32 + rg * 8 + half * 4;
            f32x4 qv = *(const f32x4*)&qsq[rbase];
            #pragma unroll
            for (int rr = 0; rr < 4; rr++) {
                int reg = rg * 4 + rr;
                size_t rowoff = (size_t)(rbase + rr) * NN;
                #pragma unroll
                for (int n = 0; n < 2; n++) {
                    out[rowoff + colb + n * 32 + l31] =
                        2.0f * acc[m][n][reg] - qv[rr] - pv[n];
                }
            }
        }
    }
}

// ---------------------------------------------------------------------------
// Phase 3 (fallback, ws too small): 128x128 kernel reading zq f32.
// ---------------------------------------------------------------------------
__global__ __launch_bounds__(256) void gemm_kernel_slow(
    const float* __restrict__ A32,
    const unsigned short* __restrict__ Bp,
    const float* __restrict__ qsq, const float* __restrict__ psq,
    float* __restrict__ out)
{
    constexpr int BM = 128, BN = 128, BK = 64, K = D_DIM, NN = C_CLASSES;
    __shared__ __align__(16) unsigned short shA[BM * BK];
    __shared__ __align__(16) unsigned short shB[BN * BK];

    const int tid  = threadIdx.x;
    const int lane = tid & 63;
    const int w    = tid >> 6;
    const int wm   = w >> 1, wn = w & 1;
    const int l31  = lane & 31, half = lane >> 5;
    const int mBase = blockIdx.y * BM;
    const int nBase = blockIdx.x * BN;

    const int srow = lane >> 3;
    const int scg  = ((lane & 7) ^ srow) * 8;

    f32x16v acc[2][2];
    #pragma unroll
    for (int i = 0; i < 2; i++)
        #pragma unroll
        for (int j = 0; j < 2; j++)
            acc[i][j] = (f32x16v)(0.0f);

    for (int k0 = 0; k0 < K; k0 += BK) {
        __syncthreads();
        #pragma unroll
        for (int t = 0; t < 4; t++) {
            int q = tid * 4 + t;
            int r = q >> 3;
            int x = q & 7;
            int cg = x ^ (r & 7);
            const float* src = A32 + (size_t)(mBase + r) * K + k0 + cg * 8;
            f32x4 v0 = *(const f32x4*)src;
            f32x4 v1 = *(const f32x4*)(src + 4);
            u16x8 p;
            p.s0 = f2bf(v0.x); p.s1 = f2bf(v0.y); p.s2 = f2bf(v0.z); p.s3 = f2bf(v0.w);
            p.s4 = f2bf(v1.x); p.s5 = f2bf(v1.y); p.s6 = f2bf(v1.z); p.s7 = f2bf(v1.w);
            *(u16x8*)&shA[r * BK + x * 8] = p;
        }
        #pragma unroll
        for (int t = 0; t < 4; t++) {
            int g = w * 4 + t;
            async_copy16(Bp + (size_t)(nBase + g * 8 + srow) * K + k0 + scg,
                         &shB[g * 8 * BK]);
        }
        __syncthreads();

        bf16x8 af[2][4], bfv[2][4];
        #pragma unroll
        for (int i = 0; i < 2; i++) {
            int ra = wm * 64 + i * 32 + l31;
            int ga = ra & 7;
            int rb = wn * 64 + i * 32 + l31;
            int gb = rb & 7;
            #pragma unroll
            for (int ks = 0; ks < 4; ks++) {
                int c = ks * 2 + half;
                af[i][ks]  = *(const bf16x8*)&shA[ra * BK + ((c ^ ga) * 8)];
                bfv[i][ks] = *(const bf16x8*)&shB[rb * BK + ((c ^ gb) * 8)];
            }
        }
        #pragma unroll
        for (int ks = 0; ks < 4; ks++)
            #pragma unroll
            for (int i = 0; i < 2; i++)
                #pragma unroll
                for (int j = 0; j < 2; j++)
                    acc[i][j] = __builtin_amdgcn_mfma_f32_32x32x16_bf16(
                        af[i][ks], bfv[j][ks], acc[i][j], 0, 0, 0);
    }

    const int rowb = mBase + wm * 64;
    const int colb = nBase + wn * 64;
    float pv[2];
    #pragma unroll
    for (int j = 0; j < 2; j++) pv[j] = psq[colb + j * 32 + l31];
    #pragma unroll
    for (int i = 0; i < 2; i++) {
        #pragma unroll
        for (int rg = 0; rg < 4; rg++) {
            int rbase = rowb + i * 32 + rg * 8 + half * 4;
            f32x4 qv = *(const f32x4*)&qsq[rbase];
            #pragma unroll
            for (int rr = 0; rr < 4; rr++) {
                int reg = rg * 4 + rr;
                size_t rowoff = (size_t)(rbase + rr) * NN;
                #pragma unroll
                for (int j = 0; j < 2; j++) {
                    out[rowoff + colb + j * 32 + l31] =
                        2.0f * acc[i][j][reg] - qv[rr] - pv[j];
                }
            }
        }
    }
}

extern "C" void kernel_launch(void* const* d_in, const int* in_sizes, int n_in,
                              void* d_out, int out_size, void* d_ws, size_t ws_size,
                              hipStream_t stream) {
    const float* zs = (const float*)d_in[0];
    const int*   ys = (const int*)d_in[1];
    const float* zq = (const float*)d_in[2];
    float* out = (float*)d_out;

    const size_t szAbf     = (size_t)N_QRY * D_DIM * 2;       // 64 MiB
    const size_t szProtos  = (size_t)C_CLASSES * D_DIM * 2;   // 1 MiB
    const size_t szQsq     = (size_t)N_QRY * 4;               // 256 KiB
    const size_t szRowlist = (size_t)C_CLASSES * SLOTS * 4;   // 576 KiB
    const size_t szPsq     = 4096;
    const size_t szCur     = 4096;

    const size_t needFast = szAbf + szProtos + szQsq + szRowlist + szPsq + szCur;
    const bool fast = ws_size >= needFast;

    char* ws = (char*)d_ws;
    unsigned short* Abf = (unsigned short*)ws;                 // fast path only
    char* base = fast ? ws + szAbf : ws;
    unsigned short* protos = (unsigned short*)base;
    float* qsq  = (float*)(base + szProtos);
    int*   rowlist = (int*)(base + szProtos + szQsq);
    float* psq  = (float*)(base + szProtos + szQsq + szRowlist);
    int*   cursors = (int*)(base + szProtos + szQsq + szRowlist + szPsq);

    // zero class cursors (capture-safe async memset)
    hipMemsetAsync(cursors, 0, C_CLASSES * sizeof(int), stream);

    // tiny scatter first, so gather blocks of the fused kernel are unblocked
    scatter_kernel<<<N_SUP / 256, 256, 0, stream>>>(ys, cursors, rowlist);

    const int fusedGrid = C_CLASSES + N_QRY / 4;
    if (fast)
        fused_qsq_gather<true><<<fusedGrid, 256, 0, stream>>>(
            zq, qsq, Abf, zs, rowlist, cursors, protos, psq);
    else
        fused_qsq_gather<false><<<fusedGrid, 256, 0, stream>>>(
            zq, qsq, nullptr, zs, rowlist, cursors, protos, psq);

    if (fast)
        gemm256_kernel<<<dim3(C_CLASSES / 256, N_QRY / 256), 512, 0, stream>>>(
            Abf, protos, qsq, psq, out);
    else
        gemm_kernel_slow<<<dim3(C_CLASSES / 128, N_QRY / 128), 256, 0, stream>>>(
            zq, protos, qsq, psq, out);
}